// Round 12
// baseline (321.381 us; speedup 1.0000x reference)
//
#include <hip/hip_runtime.h>

#define N_NODES 100000
#define N_EDGES 1000000
#define N_GRAPHS 512
#define N_CLS 10
#define BN_EPS 1e-5f

#define SCAN_NB 200   // 200 * 512 = 102400 >= N_NODES
#define NTILES 1563   // ceil(100000/64)

typedef _Float16 half8 __attribute__((ext_vector_type(8)));
typedef _Float16 half4v __attribute__((ext_vector_type(4)));
typedef float floatx4 __attribute__((ext_vector_type(4)));
typedef int intx4 __attribute__((ext_vector_type(4)));   // clang vector: OK for NT builtins

// ---------------------------------------------------------------- prep
__global__ __launch_bounds__(256) void prep_kernel(
    const float* __restrict__ x, _Float16* __restrict__ xh,
    const int* __restrict__ batch, const int* __restrict__ dstI,
    int* __restrict__ deg, int* __restrict__ rank,
    const float* __restrict__ w0a, const float* __restrict__ b0a,
    const float* __restrict__ g0, const float* __restrict__ be0,
    const float* __restrict__ m0, const float* __restrict__ v0,
    const float* __restrict__ w0b,
    const float* __restrict__ w1a, const float* __restrict__ b1a,
    const float* __restrict__ g1, const float* __restrict__ be1,
    const float* __restrict__ m1, const float* __restrict__ v1,
    const float* __restrict__ w1b,
    int* __restrict__ gstart,
    _Float16* __restrict__ wHi, _Float16* __restrict__ wLo,
    float* __restrict__ b1p0, float* __restrict__ b1p1) {
    const int gid = blockIdx.x * 256 + threadIdx.x;

    if (gid < 1600000) {  // x -> fp16 (6.4M elems as float4 -> half4)
        float4 v = ((const float4*)x)[gid];
        half4v h = {(_Float16)v.x, (_Float16)v.y, (_Float16)v.z, (_Float16)v.w};
        ((half4v*)xh)[gid] = h;
    }

    if (gid < N_EDGES)  // histogram + per-edge rank within dst bucket
        rank[gid] = atomicAdd(&deg[dstI[gid]], 1);

    if (gid <= N_NODES) {  // graph boundaries from sorted batch
        int bcur = (gid < N_NODES) ? batch[gid] : N_GRAPHS;
        int bprev = (gid > 0) ? batch[gid - 1] : -1;
        for (int g = bprev + 1; g <= bcur; ++g) gstart[g] = gid;
    }

    if (gid < 16384) {  // W frag pack: [mat(4)][k0(2)][c(4)][lane(64)][jj(8)]
        const int e = gid & 4095, mat = gid >> 12;
        const int jj = e & 7, lane = (e >> 3) & 63, c = (e >> 9) & 3, k0 = (e >> 11) & 1;
        const int k = k0 * 32 + (lane >> 4) * 8 + jj;
        const int col = c * 16 + (lane & 15);
        float val;
        if (mat == 0)      val = w0a[k * 64 + col] * (rsqrtf(v0[col] + BN_EPS) * g0[col]);
        else if (mat == 1) val = w0b[k * 64 + col];
        else if (mat == 2) val = w1a[k * 64 + col] * (rsqrtf(v1[col] + BN_EPS) * g1[col]);
        else               val = w1b[k * 64 + col];
        _Float16 hi = (_Float16)val;
        wHi[gid] = hi;
        wLo[gid] = (_Float16)(val - (float)hi);
    }

    if (gid >= 16384 && gid < 16512) {  // BN-folded biases
        int t = gid - 16384;
        if (t < 64) {
            float s = rsqrtf(v0[t] + BN_EPS) * g0[t];
            b1p0[t] = (b0a[t] - m0[t]) * s + be0[t];
        } else {
            t -= 64;
            float s = rsqrtf(v1[t] + BN_EPS) * g1[t];
            b1p1[t] = (b1a[t] - m1[t]) * s + be1[t];
        }
    }
}

// ---------------------------------------------------------------- 2-kernel scan
__global__ __launch_bounds__(256) void scanA_kernel(const int* __restrict__ deg,
                                                    int* __restrict__ bsum) {
    __shared__ int sh[256];
    const int base = blockIdx.x * 512;
    const int t = threadIdx.x;
    int a = 0, b = 0;
    if (base + t < N_NODES) a = deg[base + t];
    if (base + 256 + t < N_NODES) b = deg[base + 256 + t];
    sh[t] = a + b;
    __syncthreads();
#pragma unroll
    for (int off = 128; off > 0; off >>= 1) {
        if (t < off) sh[t] += sh[t + off];
        __syncthreads();
    }
    if (t == 0) bsum[blockIdx.x] = sh[0];
}

// scanC also re-derives its own block offset from bsum (scanB folded in).
__global__ __launch_bounds__(256) void scanC_kernel(const int* __restrict__ deg,
                                                    const int* __restrict__ bsum,
                                                    int* __restrict__ rowptr) {
    __shared__ int sh[256];
    __shared__ int sboff[256];
    const int base = blockIdx.x * 512;
    const int t = threadIdx.x;

    const int bv = (t < SCAN_NB) ? bsum[t] : 0;
    sboff[t] = bv;

    const int i0 = base + 2 * t, i1 = i0 + 1;
    const int d0 = (i0 < N_NODES) ? deg[i0] : 0;
    const int d1 = (i1 < N_NODES) ? deg[i1] : 0;
    const int p = d0 + d1;
    sh[t] = p;
    __syncthreads();
#pragma unroll
    for (int off = 1; off < 256; off <<= 1) {
        int u = (t >= off) ? sh[t - off] : 0;
        int ub = (t >= off) ? sboff[t - off] : 0;
        __syncthreads();
        sh[t] += u;
        sboff[t] += ub;
        __syncthreads();
    }
    const int myoff = (blockIdx.x == 0) ? 0 : sboff[blockIdx.x - 1];
    const int excl = myoff + sh[t] - p;
    if (i0 < N_NODES) rowptr[i0] = excl;
    if (i1 < N_NODES) rowptr[i1] = excl + d0;
    if (blockIdx.x == 0 && t == 0) rowptr[N_NODES] = N_EDGES;
}

// ---------------------------------------------------------------- fill
// 4 edges/thread. NT loads: src/dst/rank are read-once streams (don't evict
// the gather tables from L2). NT stores: sortedSrc is written-scattered-once,
// read-sequentially-once -> skipping the L2 line-allocate avoids the hidden
// 1M x 64B line-fill read+writeback (~128 MB) that plain 4B scatters cost.
__global__ __launch_bounds__(256) void fill_kernel(const intx4* __restrict__ srcI4,
                                                   const intx4* __restrict__ dstI4,
                                                   const intx4* __restrict__ rank4,
                                                   const int* __restrict__ rowptr,
                                                   int* __restrict__ sortedSrc) {
    int q = blockIdx.x * 256 + threadIdx.x;
    if (q >= N_EDGES / 4) return;
    intx4 s = __builtin_nontemporal_load(&srcI4[q]);
    intx4 d = __builtin_nontemporal_load(&dstI4[q]);
    intx4 r = __builtin_nontemporal_load(&rank4[q]);
    __builtin_nontemporal_store(s.x, &sortedSrc[rowptr[d.x] + r.x]);
    __builtin_nontemporal_store(s.y, &sortedSrc[rowptr[d.y] + r.y]);
    __builtin_nontemporal_store(s.z, &sortedSrc[rowptr[d.z] + r.z]);
    __builtin_nontemporal_store(s.w, &sortedSrc[rowptr[d.w] + r.w]);
}

// ---------------------------------------------------------------- fused conv (MFMA, fp16)
// (unchanged from R10: 69 us, ~1.8 TB/s random-gather service ceiling)
template <int POOL>
__global__ __launch_bounds__(256) void conv_mfma(
    const _Float16* __restrict__ in, const int* __restrict__ rowptr,
    const int* __restrict__ srcList,
    const _Float16* __restrict__ wH1, const _Float16* __restrict__ wL1,
    const _Float16* __restrict__ wH2, const _Float16* __restrict__ wL2,
    const float* __restrict__ b1, const float* __restrict__ b2,
    _Float16* __restrict__ out, const int* __restrict__ batch,
    float* __restrict__ pooled) {
    __shared__ __align__(16) _Float16 scratch[4][2304];  // per-wave aggH|aggL -> hH|hL -> oT
    __shared__ float pooledLoc[8 * 64];
    __shared__ int bIds[64];
    __shared__ int maxSlot;

    const int tid = threadIdx.x;
    const int j = tid & 63, wv = tid >> 6;
    const int eoff = j >> 4;
    const int lf = j & 15;
    const int base = blockIdx.x * 64;
    const int strip0 = base + wv * 16;

    if (POOL) {
        pooledLoc[tid] = 0.f;
        pooledLoc[tid + 256] = 0.f;
        if (tid == 0) maxSlot = 0;
        if (j < 16) {
            int node = strip0 + j;
            bIds[wv * 16 + j] = (node < N_NODES) ? batch[node] : -1;
        }
    }

    const int rpv = rowptr[min(strip0 + min(j, 16), N_NODES)];

    _Float16* aggH = scratch[wv];
    _Float16* aggL = scratch[wv] + 1152;

    for (int mq = 0; mq < 4; ++mq) {
        const int m0 = mq * 4;
        int rr[5];
#pragma unroll
        for (int i = 0; i < 5; ++i) rr[i] = __builtin_amdgcn_readlane(rpv, m0 + i);
        int cnt[4];
#pragma unroll
        for (int i = 0; i < 4; ++i)
            cnt[i] = (strip0 + m0 + i < N_NODES) ? rr[i + 1] - rr[i] : 0;

        float aR[4][4];
#pragma unroll
        for (int i = 0; i < 4; ++i)
#pragma unroll
            for (int q = 0; q < 4; ++q) aR[i][q] = 0.f;

        half4v sS[4];
#pragma unroll
        for (int i = 0; i < 4; ++i) {
            sS[i] = (half4v){0, 0, 0, 0};
            if (eoff == 0 && strip0 + m0 + i < N_NODES)
                sS[i] = *(const half4v*)(in + (size_t)(strip0 + m0 + i) * 64 + lf * 4);
        }
        half4v vT[4][4];
#pragma unroll
        for (int i = 0; i < 4; ++i) {
            const int g = (min(cnt[i], 16) + 3) >> 2;
#pragma unroll
            for (int k = 0; k < 4; ++k) {
                vT[i][k] = (half4v){0, 0, 0, 0};
                if (k < g) {
                    int ec = min(4 * k + eoff, cnt[i] - 1);
                    int id = srcList[rr[i] + ec];
                    vT[i][k] = *(const half4v*)(in + (size_t)id * 64 + lf * 4);
                }
            }
        }
#pragma unroll
        for (int i = 0; i < 4; ++i) {
#pragma unroll
            for (int k = 0; k < 4; ++k) {
                if (4 * k + eoff < cnt[i]) {
                    aR[i][0] += (float)vT[i][k].x; aR[i][1] += (float)vT[i][k].y;
                    aR[i][2] += (float)vT[i][k].z; aR[i][3] += (float)vT[i][k].w;
                }
            }
        }
#pragma unroll
        for (int i = 0; i < 4; ++i) {
            for (int eb = 16; eb < cnt[i]; eb += 16) {
#pragma unroll
                for (int k = 0; k < 4; ++k) {
                    int e_ = eb + 4 * k + eoff;
                    if (e_ < cnt[i]) {
                        int id = srcList[rr[i] + e_];
                        half4v t = *(const half4v*)(in + (size_t)id * 64 + lf * 4);
                        aR[i][0] += (float)t.x; aR[i][1] += (float)t.y;
                        aR[i][2] += (float)t.z; aR[i][3] += (float)t.w;
                    }
                }
            }
        }
#pragma unroll
        for (int i = 0; i < 4; ++i) {
            if (eoff == 0) {
                aR[i][0] += (float)sS[i].x; aR[i][1] += (float)sS[i].y;
                aR[i][2] += (float)sS[i].z; aR[i][3] += (float)sS[i].w;
            }
#pragma unroll
            for (int q = 0; q < 4; ++q) {
                aR[i][q] += __shfl_xor(aR[i][q], 16, 64);
                aR[i][q] += __shfl_xor(aR[i][q], 32, 64);
            }
            if (j < 16) {
                half4v hi, lo;
#pragma unroll
                for (int q = 0; q < 4; ++q) {
                    hi[q] = (_Float16)aR[i][q];
                    lo[q] = (_Float16)(aR[i][q] - (float)hi[q]);
                }
                *(half4v*)(aggH + (m0 + i) * 72 + 4 * j) = hi;
                *(half4v*)(aggL + (m0 + i) * 72 + 4 * j) = lo;
            }
        }
    }

    const int l15 = j & 15, quad = j >> 4;
    const floatx4 vzero = {0.f, 0.f, 0.f, 0.f};

    floatx4 acc[4] = {vzero, vzero, vzero, vzero};
    {
        const _Float16* aH0 = aggH + l15 * 72 + quad * 8;
        const _Float16* aL0 = aggL + l15 * 72 + quad * 8;
#pragma unroll
        for (int k0 = 0; k0 < 2; ++k0) {
            half8 aH = *(const half8*)(aH0 + k0 * 32);
            half8 aL = *(const half8*)(aL0 + k0 * 32);
#pragma unroll
            for (int c = 0; c < 4; ++c) {
                const int fo = ((k0 * 4 + c) * 64 + j) * 8;
                half8 bH = *(const half8*)(wH1 + fo);
                half8 bL = *(const half8*)(wL1 + fo);
                acc[c] = __builtin_amdgcn_mfma_f32_16x16x32_f16(aH, bH, acc[c], 0, 0, 0);
                acc[c] = __builtin_amdgcn_mfma_f32_16x16x32_f16(aL, bH, acc[c], 0, 0, 0);
                acc[c] = __builtin_amdgcn_mfma_f32_16x16x32_f16(aH, bL, acc[c], 0, 0, 0);
            }
        }
    }
    _Float16* hH = aggH;
    _Float16* hL = aggL;
#pragma unroll
    for (int c = 0; c < 4; ++c) {
        const float bv = b1[c * 16 + l15];
#pragma unroll
        for (int r = 0; r < 4; ++r) {
            const int row = quad * 4 + r, col = c * 16 + l15;
            float v = acc[c][r] + bv;
            v = fmaxf(v, 0.f);
            const _Float16 hi = (_Float16)v;
            hH[row * 72 + col] = hi;
            hL[row * 72 + col] = (_Float16)(v - (float)hi);
        }
    }

    floatx4 acc2[4] = {vzero, vzero, vzero, vzero};
    {
        const _Float16* aH0 = hH + l15 * 72 + quad * 8;
        const _Float16* aL0 = hL + l15 * 72 + quad * 8;
#pragma unroll
        for (int k0 = 0; k0 < 2; ++k0) {
            half8 aH = *(const half8*)(aH0 + k0 * 32);
            half8 aL = *(const half8*)(aL0 + k0 * 32);
#pragma unroll
            for (int c = 0; c < 4; ++c) {
                const int fo = ((k0 * 4 + c) * 64 + j) * 8;
                half8 bH = *(const half8*)(wH2 + fo);
                half8 bL = *(const half8*)(wL2 + fo);
                acc2[c] = __builtin_amdgcn_mfma_f32_16x16x32_f16(aH, bH, acc2[c], 0, 0, 0);
                acc2[c] = __builtin_amdgcn_mfma_f32_16x16x32_f16(aL, bH, acc2[c], 0, 0, 0);
                acc2[c] = __builtin_amdgcn_mfma_f32_16x16x32_f16(aH, bL, acc2[c], 0, 0, 0);
            }
        }
    }

    if (!POOL) {
#pragma unroll
        for (int c = 0; c < 4; ++c) {
            const float bv = b2[c * 16 + l15];
#pragma unroll
            for (int r = 0; r < 4; ++r) {
                const int node = strip0 + quad * 4 + r;
                if (node < N_NODES)
                    out[(size_t)node * 64 + c * 16 + l15] =
                        (_Float16)fmaxf(acc2[c][r] + bv, 0.f);
            }
        }
    } else {
        float* oT = (float*)scratch[wv];
#pragma unroll
        for (int c = 0; c < 4; ++c) {
            const float bv = b2[c * 16 + l15];
#pragma unroll
            for (int r = 0; r < 4; ++r)
                oT[(quad * 4 + r) * 66 + c * 16 + l15] = acc2[c][r] + bv;
        }
        __syncthreads();
        const int b0 = bIds[0];
        int curB = -1;
        float accv = 0.f;
        for (int r = 0; r < 16; ++r) {
            const int b = bIds[wv * 16 + r];
            if (b < 0) break;
            const float v = oT[r * 66 + j];
            if (b != curB) {
                if (curB >= 0) {
                    const int s = curB - b0;
                    if (s >= 0 && s < 8) {
                        atomicAdd(&pooledLoc[s * 64 + j], accv);
                        if (j == 0) atomicMax(&maxSlot, s);
                    } else {
                        atomicAdd(&pooled[curB * 64 + j], accv);
                    }
                }
                curB = b;
                accv = v;
            } else {
                accv += v;
            }
        }
        if (curB >= 0) {
            const int s = curB - b0;
            if (s >= 0 && s < 8) {
                atomicAdd(&pooledLoc[s * 64 + j], accv);
                if (j == 0) atomicMax(&maxSlot, s);
            } else {
                atomicAdd(&pooled[curB * 64 + j], accv);
            }
        }
        __syncthreads();
        if (b0 >= 0) {
            const int ns = maxSlot + 1;
            for (int s = wv; s < ns; s += 4)
                atomicAdd(&pooled[(b0 + s) * 64 + j], pooledLoc[s * 64 + j]);
        }
    }
}

// ---------------------------------------------------------------- classifier
__global__ __launch_bounds__(64) void classifier_kernel(const float* __restrict__ pooled,
                                                        const int* __restrict__ gstart,
                                                        const float* __restrict__ wc,
                                                        const float* __restrict__ bc,
                                                        float* __restrict__ out) {
    const int g = blockIdx.x;
    const int j = threadIdx.x;
    const float c = fmaxf((float)(gstart[g + 1] - gstart[g]), 1.f);
    const float mean = pooled[g * 64 + j] / c;
#pragma unroll
    for (int cc = 0; cc < N_CLS; ++cc) {
        float p = mean * wc[j * N_CLS + cc];
#pragma unroll
        for (int off = 32; off > 0; off >>= 1) p += __shfl_down(p, off, 64);
        if (j == 0) out[g * N_CLS + cc] = p + bc[cc];
    }
}

// ---------------------------------------------------------------- launch

extern "C" void kernel_launch(void* const* d_in, const int* in_sizes, int n_in,
                              void* d_out, int out_size, void* d_ws, size_t ws_size,
                              hipStream_t stream) {
    const float* x   = (const float*)d_in[0];
    const int*   ei  = (const int*)d_in[1];
    const int* batch = (const int*)d_in[2];
    const float* w0a = (const float*)d_in[3];
    const float* b0a = (const float*)d_in[4];
    const float* g0  = (const float*)d_in[5];
    const float* be0 = (const float*)d_in[6];
    const float* m0  = (const float*)d_in[7];
    const float* v0  = (const float*)d_in[8];
    const float* w0b = (const float*)d_in[9];
    const float* b0b = (const float*)d_in[10];
    const float* w1a = (const float*)d_in[11];
    const float* b1a = (const float*)d_in[12];
    const float* g1  = (const float*)d_in[13];
    const float* be1 = (const float*)d_in[14];
    const float* m1  = (const float*)d_in[15];
    const float* v1  = (const float*)d_in[16];
    const float* w1b = (const float*)d_in[17];
    const float* b1b = (const float*)d_in[18];
    const float* wc  = (const float*)d_in[19];
    const float* bc  = (const float*)d_in[20];
    float* out = (float*)d_out;

    const int* srcI = ei;
    const int* dstI = ei + N_EDGES;

    // workspace layout, offsets in 4-byte units
    int* ws = (int*)d_ws;
    int*      deg       = ws;                              // 100000
    int*      bsum      = ws + 100000;                     // 200
    float*    pooled    = (float*)(ws + 100404);           // 32768
    int*      rowptr    = ws + 133172;                     // 100001
    int*      rank      = ws + 233176;                     // 1000000 (16B aligned)
    int*      sortedSrc = ws + 1233176;                    // 1000000
    _Float16* xh        = (_Float16*)(ws + 2233176);       // 6400000 halves
    _Float16* h1        = (_Float16*)(ws + 5433176);       // 6400000 halves
    float*    b1p0      = (float*)(ws + 8633176);          // 64
    float*    b1p1      = (float*)(ws + 8633240);          // 64
    int*      gstart    = ws + 8633304;                    // 513
    _Float16* wHi       = (_Float16*)(ws + 8633820);       // 16384 halves
    _Float16* wLo       = (_Float16*)(ws + 8642012);       // 16384 halves

    (void)hipMemsetAsync((void*)deg, 0, 133172 * sizeof(int), stream);
    prep_kernel<<<6250, 256, 0, stream>>>(x, xh, batch, dstI, deg, rank,
                                          w0a, b0a, g0, be0, m0, v0, w0b,
                                          w1a, b1a, g1, be1, m1, v1, w1b,
                                          gstart, wHi, wLo, b1p0, b1p1);

    scanA_kernel<<<SCAN_NB, 256, 0, stream>>>(deg, bsum);
    scanC_kernel<<<SCAN_NB, 256, 0, stream>>>(deg, bsum, rowptr);
    fill_kernel<<<(N_EDGES / 4 + 255) / 256, 256, 0, stream>>>(
        (const intx4*)srcI, (const intx4*)dstI, (const intx4*)rank, rowptr, sortedSrc);

    // conv0: h1 = relu(mlp0(x + gather(x)))   [fp16 features]
    conv_mfma<0><<<NTILES, 256, 0, stream>>>(xh, rowptr, sortedSrc,
                                             wHi, wLo, wHi + 4096, wLo + 4096,
                                             b1p0, b0b, h1, nullptr, nullptr);

    // conv1: pooled += mlp1(h1 + gather(h1))
    conv_mfma<1><<<NTILES, 256, 0, stream>>>(h1, rowptr, sortedSrc,
                                             wHi + 8192, wLo + 8192, wHi + 12288, wLo + 12288,
                                             b1p1, b1b, nullptr, batch, pooled);

    classifier_kernel<<<N_GRAPHS, 64, 0, stream>>>(pooled, gstart, wc, bc, out);
}

// Round 13
// 292.042 us; speedup vs baseline: 1.1005x; 1.1005x over previous
//
#include <hip/hip_runtime.h>

#define N_NODES 100000
#define N_EDGES 1000000
#define N_GRAPHS 512
#define N_CLS 10
#define BN_EPS 1e-5f

#define SCAN_NB 200    // 200 * 512 = 102400 >= N_NODES
#define NTILES2 3125   // 100000 / 32 exactly (32-node tiles, no tail)

typedef _Float16 half8 __attribute__((ext_vector_type(8)));
typedef _Float16 half4v __attribute__((ext_vector_type(4)));
typedef float floatx4 __attribute__((ext_vector_type(4)));

// ---------------------------------------------------------------- prep
__global__ __launch_bounds__(256) void prep_kernel(
    const float* __restrict__ x, _Float16* __restrict__ xh,
    const int* __restrict__ batch, const int* __restrict__ dstI,
    int* __restrict__ deg, int* __restrict__ rank,
    const float* __restrict__ w0a, const float* __restrict__ b0a,
    const float* __restrict__ g0, const float* __restrict__ be0,
    const float* __restrict__ m0, const float* __restrict__ v0,
    const float* __restrict__ w0b,
    const float* __restrict__ w1a, const float* __restrict__ b1a,
    const float* __restrict__ g1, const float* __restrict__ be1,
    const float* __restrict__ m1, const float* __restrict__ v1,
    const float* __restrict__ w1b,
    int* __restrict__ gstart,
    _Float16* __restrict__ wHi, _Float16* __restrict__ wLo,
    float* __restrict__ b1p0, float* __restrict__ b1p1) {
    const int gid = blockIdx.x * 256 + threadIdx.x;

    if (gid < 1600000) {  // x -> fp16 (6.4M elems as float4 -> half4)
        float4 v = ((const float4*)x)[gid];
        half4v h = {(_Float16)v.x, (_Float16)v.y, (_Float16)v.z, (_Float16)v.w};
        ((half4v*)xh)[gid] = h;
    }

    if (gid < N_EDGES)  // histogram + per-edge rank within dst bucket
        rank[gid] = atomicAdd(&deg[dstI[gid]], 1);

    if (gid <= N_NODES) {  // graph boundaries from sorted batch
        int bcur = (gid < N_NODES) ? batch[gid] : N_GRAPHS;
        int bprev = (gid > 0) ? batch[gid - 1] : -1;
        for (int g = bprev + 1; g <= bcur; ++g) gstart[g] = gid;
    }

    if (gid < 16384) {  // W frag pack: [mat(4)][k0(2)][c(4)][lane(64)][jj(8)]
        const int e = gid & 4095, mat = gid >> 12;
        const int jj = e & 7, lane = (e >> 3) & 63, c = (e >> 9) & 3, k0 = (e >> 11) & 1;
        const int k = k0 * 32 + (lane >> 4) * 8 + jj;
        const int col = c * 16 + (lane & 15);
        float val;
        if (mat == 0)      val = w0a[k * 64 + col] * (rsqrtf(v0[col] + BN_EPS) * g0[col]);
        else if (mat == 1) val = w0b[k * 64 + col];
        else if (mat == 2) val = w1a[k * 64 + col] * (rsqrtf(v1[col] + BN_EPS) * g1[col]);
        else               val = w1b[k * 64 + col];
        _Float16 hi = (_Float16)val;
        wHi[gid] = hi;
        wLo[gid] = (_Float16)(val - (float)hi);
    }

    if (gid >= 16384 && gid < 16512) {  // BN-folded biases
        int t = gid - 16384;
        if (t < 64) {
            float s = rsqrtf(v0[t] + BN_EPS) * g0[t];
            b1p0[t] = (b0a[t] - m0[t]) * s + be0[t];
        } else {
            t -= 64;
            float s = rsqrtf(v1[t] + BN_EPS) * g1[t];
            b1p1[t] = (b1a[t] - m1[t]) * s + be1[t];
        }
    }
}

// ---------------------------------------------------------------- 2-kernel scan
__global__ __launch_bounds__(256) void scanA_kernel(const int* __restrict__ deg,
                                                    int* __restrict__ bsum) {
    __shared__ int sh[256];
    const int base = blockIdx.x * 512;
    const int t = threadIdx.x;
    int a = 0, b = 0;
    if (base + t < N_NODES) a = deg[base + t];
    if (base + 256 + t < N_NODES) b = deg[base + 256 + t];
    sh[t] = a + b;
    __syncthreads();
#pragma unroll
    for (int off = 128; off > 0; off >>= 1) {
        if (t < off) sh[t] += sh[t + off];
        __syncthreads();
    }
    if (t == 0) bsum[blockIdx.x] = sh[0];
}

// scanC re-derives its own block offset from bsum (scanB folded in).
__global__ __launch_bounds__(256) void scanC_kernel(const int* __restrict__ deg,
                                                    const int* __restrict__ bsum,
                                                    int* __restrict__ rowptr) {
    __shared__ int sh[256];
    __shared__ int sboff[256];
    const int base = blockIdx.x * 512;
    const int t = threadIdx.x;

    const int bv = (t < SCAN_NB) ? bsum[t] : 0;
    sboff[t] = bv;

    const int i0 = base + 2 * t, i1 = i0 + 1;
    const int d0 = (i0 < N_NODES) ? deg[i0] : 0;
    const int d1 = (i1 < N_NODES) ? deg[i1] : 0;
    const int p = d0 + d1;
    sh[t] = p;
    __syncthreads();
#pragma unroll
    for (int off = 1; off < 256; off <<= 1) {
        int u = (t >= off) ? sh[t - off] : 0;
        int ub = (t >= off) ? sboff[t - off] : 0;
        __syncthreads();
        sh[t] += u;
        sboff[t] += ub;
        __syncthreads();
    }
    const int myoff = (blockIdx.x == 0) ? 0 : sboff[blockIdx.x - 1];
    const int excl = myoff + sh[t] - p;
    if (i0 < N_NODES) rowptr[i0] = excl;
    if (i1 < N_NODES) rowptr[i1] = excl + d0;
    if (blockIdx.x == 0 && t == 0) rowptr[N_NODES] = N_EDGES;
}

// ---------------------------------------------------------------- fill (R10 exact: plain ops)
__global__ __launch_bounds__(256) void fill_kernel(const int* __restrict__ srcI,
                                                   const int* __restrict__ dstI,
                                                   const int* __restrict__ rank,
                                                   const int* __restrict__ rowptr,
                                                   int* __restrict__ sortedSrc) {
    int e = blockIdx.x * 256 + threadIdx.x;
    if (e >= N_EDGES) return;
    sortedSrc[rowptr[dstI[e]] + rank[e]] = srcI[e];
}

// ---------------------------------------------------------------- fused conv (MFMA, fp16)
// 32-node tiles, 2 waves/block, 128 threads, grid 3125 (exact, no tail):
// ~12.2 blocks/CU avg with 13 resident possible -> near-full residency, 6% tail.
// Per-wave: 16-node strip; lane = (edge-subindex j>>4, feature-chunk j&15),
// half4/lane -> 4 full 128B rows per wave instruction; 4 rows x 4 groups in
// flight per issue batch. NO device-scope fences (R8 lesson).
template <int POOL>
__global__ __launch_bounds__(128) void conv_mfma(
    const _Float16* __restrict__ in, const int* __restrict__ rowptr,
    const int* __restrict__ srcList,
    const _Float16* __restrict__ wH1, const _Float16* __restrict__ wL1,
    const _Float16* __restrict__ wH2, const _Float16* __restrict__ wL2,
    const float* __restrict__ b1, const float* __restrict__ b2,
    _Float16* __restrict__ out, const int* __restrict__ batch,
    float* __restrict__ pooled) {
    __shared__ __align__(16) _Float16 scratch[2][2304];  // per-wave aggH|aggL -> hH|hL -> oT
    __shared__ float pooledLoc[8 * 64];
    __shared__ int bIds[32];
    __shared__ int maxSlot;

    const int tid = threadIdx.x;
    const int j = tid & 63, wv = tid >> 6;   // 2 waves
    const int eoff = j >> 4;
    const int lf = j & 15;
    const int base = blockIdx.x * 32;
    const int strip0 = base + wv * 16;       // always < N_NODES (3125*32 = 100000 exact)

    if (POOL) {
#pragma unroll
        for (int q = 0; q < 4; ++q) pooledLoc[tid + q * 128] = 0.f;
        if (tid == 0) maxSlot = 0;
        if (j < 16) bIds[wv * 16 + j] = batch[strip0 + j];
    }

    const int rpv = rowptr[strip0 + min(j, 16)];

    _Float16* aggH = scratch[wv];
    _Float16* aggL = scratch[wv] + 1152;

    for (int mq = 0; mq < 4; ++mq) {
        const int m0 = mq * 4;
        int rr[5];
#pragma unroll
        for (int i = 0; i < 5; ++i) rr[i] = __builtin_amdgcn_readlane(rpv, m0 + i);
        int cnt[4];
#pragma unroll
        for (int i = 0; i < 4; ++i) cnt[i] = rr[i + 1] - rr[i];

        float aR[4][4];
#pragma unroll
        for (int i = 0; i < 4; ++i)
#pragma unroll
            for (int q = 0; q < 4; ++q) aR[i][q] = 0.f;

        half4v sS[4];
#pragma unroll
        for (int i = 0; i < 4; ++i) {
            sS[i] = (half4v){0, 0, 0, 0};
            if (eoff == 0)
                sS[i] = *(const half4v*)(in + (size_t)(strip0 + m0 + i) * 64 + lf * 4);
        }
        half4v vT[4][4];
#pragma unroll
        for (int i = 0; i < 4; ++i) {
            const int g = (min(cnt[i], 16) + 3) >> 2;
#pragma unroll
            for (int k = 0; k < 4; ++k) {
                vT[i][k] = (half4v){0, 0, 0, 0};
                if (k < g) {
                    int ec = min(4 * k + eoff, cnt[i] - 1);
                    int id = srcList[rr[i] + ec];
                    vT[i][k] = *(const half4v*)(in + (size_t)id * 64 + lf * 4);
                }
            }
        }
#pragma unroll
        for (int i = 0; i < 4; ++i) {
#pragma unroll
            for (int k = 0; k < 4; ++k) {
                if (4 * k + eoff < cnt[i]) {
                    aR[i][0] += (float)vT[i][k].x; aR[i][1] += (float)vT[i][k].y;
                    aR[i][2] += (float)vT[i][k].z; aR[i][3] += (float)vT[i][k].w;
                }
            }
        }
#pragma unroll
        for (int i = 0; i < 4; ++i) {
            for (int eb = 16; eb < cnt[i]; eb += 16) {
#pragma unroll
                for (int k = 0; k < 4; ++k) {
                    int e_ = eb + 4 * k + eoff;
                    if (e_ < cnt[i]) {
                        int id = srcList[rr[i] + e_];
                        half4v t = *(const half4v*)(in + (size_t)id * 64 + lf * 4);
                        aR[i][0] += (float)t.x; aR[i][1] += (float)t.y;
                        aR[i][2] += (float)t.z; aR[i][3] += (float)t.w;
                    }
                }
            }
        }
#pragma unroll
        for (int i = 0; i < 4; ++i) {
            if (eoff == 0) {
                aR[i][0] += (float)sS[i].x; aR[i][1] += (float)sS[i].y;
                aR[i][2] += (float)sS[i].z; aR[i][3] += (float)sS[i].w;
            }
#pragma unroll
            for (int q = 0; q < 4; ++q) {
                aR[i][q] += __shfl_xor(aR[i][q], 16, 64);
                aR[i][q] += __shfl_xor(aR[i][q], 32, 64);
            }
            if (j < 16) {
                half4v hi, lo;
#pragma unroll
                for (int q = 0; q < 4; ++q) {
                    hi[q] = (_Float16)aR[i][q];
                    lo[q] = (_Float16)(aR[i][q] - (float)hi[q]);
                }
                *(half4v*)(aggH + (m0 + i) * 72 + 4 * j) = hi;
                *(half4v*)(aggL + (m0 + i) * 72 + 4 * j) = lo;
            }
        }
    }

    const int l15 = j & 15, quad = j >> 4;
    const floatx4 vzero = {0.f, 0.f, 0.f, 0.f};

    floatx4 acc[4] = {vzero, vzero, vzero, vzero};
    {
        const _Float16* aH0 = aggH + l15 * 72 + quad * 8;
        const _Float16* aL0 = aggL + l15 * 72 + quad * 8;
#pragma unroll
        for (int k0 = 0; k0 < 2; ++k0) {
            half8 aH = *(const half8*)(aH0 + k0 * 32);
            half8 aL = *(const half8*)(aL0 + k0 * 32);
#pragma unroll
            for (int c = 0; c < 4; ++c) {
                const int fo = ((k0 * 4 + c) * 64 + j) * 8;
                half8 bH = *(const half8*)(wH1 + fo);
                half8 bL = *(const half8*)(wL1 + fo);
                acc[c] = __builtin_amdgcn_mfma_f32_16x16x32_f16(aH, bH, acc[c], 0, 0, 0);
                acc[c] = __builtin_amdgcn_mfma_f32_16x16x32_f16(aL, bH, acc[c], 0, 0, 0);
                acc[c] = __builtin_amdgcn_mfma_f32_16x16x32_f16(aH, bL, acc[c], 0, 0, 0);
            }
        }
    }
    _Float16* hH = aggH;
    _Float16* hL = aggL;
#pragma unroll
    for (int c = 0; c < 4; ++c) {
        const float bv = b1[c * 16 + l15];
#pragma unroll
        for (int r = 0; r < 4; ++r) {
            const int row = quad * 4 + r, col = c * 16 + l15;
            float v = acc[c][r] + bv;
            v = fmaxf(v, 0.f);
            const _Float16 hi = (_Float16)v;
            hH[row * 72 + col] = hi;
            hL[row * 72 + col] = (_Float16)(v - (float)hi);
        }
    }

    floatx4 acc2[4] = {vzero, vzero, vzero, vzero};
    {
        const _Float16* aH0 = hH + l15 * 72 + quad * 8;
        const _Float16* aL0 = hL + l15 * 72 + quad * 8;
#pragma unroll
        for (int k0 = 0; k0 < 2; ++k0) {
            half8 aH = *(const half8*)(aH0 + k0 * 32);
            half8 aL = *(const half8*)(aL0 + k0 * 32);
#pragma unroll
            for (int c = 0; c < 4; ++c) {
                const int fo = ((k0 * 4 + c) * 64 + j) * 8;
                half8 bH = *(const half8*)(wH2 + fo);
                half8 bL = *(const half8*)(wL2 + fo);
                acc2[c] = __builtin_amdgcn_mfma_f32_16x16x32_f16(aH, bH, acc2[c], 0, 0, 0);
                acc2[c] = __builtin_amdgcn_mfma_f32_16x16x32_f16(aL, bH, acc2[c], 0, 0, 0);
                acc2[c] = __builtin_amdgcn_mfma_f32_16x16x32_f16(aH, bL, acc2[c], 0, 0, 0);
            }
        }
    }

    if (!POOL) {
#pragma unroll
        for (int c = 0; c < 4; ++c) {
            const float bv = b2[c * 16 + l15];
#pragma unroll
            for (int r = 0; r < 4; ++r) {
                const int node = strip0 + quad * 4 + r;
                out[(size_t)node * 64 + c * 16 + l15] =
                    (_Float16)fmaxf(acc2[c][r] + bv, 0.f);
            }
        }
    } else {
        float* oT = (float*)scratch[wv];
#pragma unroll
        for (int c = 0; c < 4; ++c) {
            const float bv = b2[c * 16 + l15];
#pragma unroll
            for (int r = 0; r < 4; ++r)
                oT[(quad * 4 + r) * 66 + c * 16 + l15] = acc2[c][r] + bv;
        }
        __syncthreads();
        const int b0 = bIds[0];
        int curB = -1;
        float accv = 0.f;
        for (int r = 0; r < 16; ++r) {
            const int b = bIds[wv * 16 + r];  // wave-uniform
            const float v = oT[r * 66 + j];
            if (b != curB) {
                if (curB >= 0) {
                    const int s = curB - b0;
                    if (s >= 0 && s < 8) {
                        atomicAdd(&pooledLoc[s * 64 + j], accv);
                        if (j == 0) atomicMax(&maxSlot, s);
                    } else {
                        atomicAdd(&pooled[curB * 64 + j], accv);
                    }
                }
                curB = b;
                accv = v;
            } else {
                accv += v;
            }
        }
        {
            const int s = curB - b0;
            if (s >= 0 && s < 8) {
                atomicAdd(&pooledLoc[s * 64 + j], accv);
                if (j == 0) atomicMax(&maxSlot, s);
            } else {
                atomicAdd(&pooled[curB * 64 + j], accv);
            }
        }
        __syncthreads();
        const int ns = maxSlot + 1;
        for (int s = wv; s < ns; s += 2)
            atomicAdd(&pooled[(b0 + s) * 64 + j], pooledLoc[s * 64 + j]);
    }
}

// ---------------------------------------------------------------- classifier
__global__ __launch_bounds__(64) void classifier_kernel(const float* __restrict__ pooled,
                                                        const int* __restrict__ gstart,
                                                        const float* __restrict__ wc,
                                                        const float* __restrict__ bc,
                                                        float* __restrict__ out) {
    const int g = blockIdx.x;
    const int j = threadIdx.x;
    const float c = fmaxf((float)(gstart[g + 1] - gstart[g]), 1.f);
    const float mean = pooled[g * 64 + j] / c;
#pragma unroll
    for (int cc = 0; cc < N_CLS; ++cc) {
        float p = mean * wc[j * N_CLS + cc];
#pragma unroll
        for (int off = 32; off > 0; off >>= 1) p += __shfl_down(p, off, 64);
        if (j == 0) out[g * N_CLS + cc] = p + bc[cc];
    }
}

// ---------------------------------------------------------------- launch

extern "C" void kernel_launch(void* const* d_in, const int* in_sizes, int n_in,
                              void* d_out, int out_size, void* d_ws, size_t ws_size,
                              hipStream_t stream) {
    const float* x   = (const float*)d_in[0];
    const int*   ei  = (const int*)d_in[1];
    const int* batch = (const int*)d_in[2];
    const float* w0a = (const float*)d_in[3];
    const float* b0a = (const float*)d_in[4];
    const float* g0  = (const float*)d_in[5];
    const float* be0 = (const float*)d_in[6];
    const float* m0  = (const float*)d_in[7];
    const float* v0  = (const float*)d_in[8];
    const float* w0b = (const float*)d_in[9];
    const float* b0b = (const float*)d_in[10];
    const float* w1a = (const float*)d_in[11];
    const float* b1a = (const float*)d_in[12];
    const float* g1  = (const float*)d_in[13];
    const float* be1 = (const float*)d_in[14];
    const float* m1  = (const float*)d_in[15];
    const float* v1  = (const float*)d_in[16];
    const float* w1b = (const float*)d_in[17];
    const float* b1b = (const float*)d_in[18];
    const float* wc  = (const float*)d_in[19];
    const float* bc  = (const float*)d_in[20];
    float* out = (float*)d_out;

    const int* srcI = ei;
    const int* dstI = ei + N_EDGES;

    // workspace layout, offsets in 4-byte units
    int* ws = (int*)d_ws;
    int*      deg       = ws;                              // 100000
    int*      bsum      = ws + 100000;                     // 200
    float*    pooled    = (float*)(ws + 100404);           // 32768
    int*      rowptr    = ws + 133172;                     // 100001
    int*      rank      = ws + 233176;                     // 1000000
    int*      sortedSrc = ws + 1233176;                    // 1000000
    _Float16* xh        = (_Float16*)(ws + 2233176);       // 6400000 halves
    _Float16* h1        = (_Float16*)(ws + 5433176);       // 6400000 halves
    float*    b1p0      = (float*)(ws + 8633176);          // 64
    float*    b1p1      = (float*)(ws + 8633240);          // 64
    int*      gstart    = ws + 8633304;                    // 513
    _Float16* wHi       = (_Float16*)(ws + 8633820);       // 16384 halves
    _Float16* wLo       = (_Float16*)(ws + 8642012);       // 16384 halves

    (void)hipMemsetAsync((void*)deg, 0, 133172 * sizeof(int), stream);
    prep_kernel<<<6250, 256, 0, stream>>>(x, xh, batch, dstI, deg, rank,
                                          w0a, b0a, g0, be0, m0, v0, w0b,
                                          w1a, b1a, g1, be1, m1, v1, w1b,
                                          gstart, wHi, wLo, b1p0, b1p1);

    scanA_kernel<<<SCAN_NB, 256, 0, stream>>>(deg, bsum);
    scanC_kernel<<<SCAN_NB, 256, 0, stream>>>(deg, bsum, rowptr);
    fill_kernel<<<(N_EDGES + 255) / 256, 256, 0, stream>>>(srcI, dstI, rank, rowptr, sortedSrc);

    // conv0: h1 = relu(mlp0(x + gather(x)))   [fp16 features]
    conv_mfma<0><<<NTILES2, 128, 0, stream>>>(xh, rowptr, sortedSrc,
                                              wHi, wLo, wHi + 4096, wLo + 4096,
                                              b1p0, b0b, h1, nullptr, nullptr);

    // conv1: pooled += mlp1(h1 + gather(h1))
    conv_mfma<1><<<NTILES2, 128, 0, stream>>>(h1, rowptr, sortedSrc,
                                              wHi + 8192, wLo + 8192, wHi + 12288, wLo + 12288,
                                              b1p1, b1b, nullptr, batch, pooled);

    classifier_kernel<<<N_GRAPHS, 64, 0, stream>>>(pooled, gstart, wc, bc, out);
}